// Round 1
// baseline (258.561 us; speedup 1.0000x reference)
//
#include <hip/hip_runtime.h>

typedef float f32x4 __attribute__((ext_vector_type(4)));
typedef __bf16 bf16x8_t __attribute__((ext_vector_type(8)));
typedef __bf16 bf16x4_t __attribute__((ext_vector_type(4)));

#define GLOAD16(gptr, lptr)                                                        \
  __builtin_amdgcn_global_load_lds((const __attribute__((address_space(1))) void*)(gptr), \
                                   (__attribute__((address_space(3))) void*)(lptr), 16, 0, 0)

// ---------------- prep kernels ----------------

__global__ __launch_bounds__(256) void k_cvt_x(const float* __restrict__ x,
                                               __bf16* __restrict__ xb, int n4) {
  int i = blockIdx.x * 256 + threadIdx.x;
  if (i >= n4) return;
  float4 a = reinterpret_cast<const float4*>(x)[i];
  bf16x4_t o;
  o[0] = (__bf16)a.x; o[1] = (__bf16)a.y; o[2] = (__bf16)a.z; o[3] = (__bf16)a.w;
  reinterpret_cast<bf16x4_t*>(xb)[i] = o;
}

// W_p[h][d][e] (fp32, [16][1024][64]) -> WB1[(p*1024 + h*64 + e)][d] bf16
__global__ __launch_bounds__(256) void k_packw1(const float* __restrict__ wq,
                                                const float* __restrict__ wk,
                                                const float* __restrict__ wv,
                                                __bf16* __restrict__ out) {
  __shared__ __bf16 tr[64][64];  // [e][dd]
  int p = blockIdx.z, h = blockIdx.y, dt = blockIdx.x;
  const float* W = (p == 0) ? wq : (p == 1) ? wk : wv;
  int t = threadIdx.x;
#pragma unroll
  for (int i = 0; i < 4; ++i) {
    int fl = i * 1024 + t * 4;    // d-major over 64x64 tile
    int dd = fl >> 6, e = fl & 63;
    float4 a = *reinterpret_cast<const float4*>(W + ((size_t)(h * 1024 + dt * 64 + dd) * 64 + e));
    tr[e + 0][dd] = (__bf16)a.x; tr[e + 1][dd] = (__bf16)a.y;
    tr[e + 2][dd] = (__bf16)a.z; tr[e + 3][dd] = (__bf16)a.w;
  }
  __syncthreads();
#pragma unroll
  for (int i = 0; i < 2; ++i) {
    int ch = i * 256 + t;         // 512 chunks of 8 elems
    int e = ch >> 3, c8 = ch & 7;
    *reinterpret_cast<bf16x8_t*>(out + ((size_t)(p * 1024 + h * 64 + e) * 1024 + dt * 64 + c8 * 8)) =
        *reinterpret_cast<const bf16x8_t*>(&tr[e][c8 * 8]);
  }
}

// W_O[h][e][n] (fp32, [16][64][1024]) -> WB2[n][h*64 + e] bf16
__global__ __launch_bounds__(256) void k_packw2(const float* __restrict__ wo,
                                                __bf16* __restrict__ out) {
  __shared__ __bf16 tr[64][64];  // [nn][e]
  int h = blockIdx.y, nt = blockIdx.x;
  int t = threadIdx.x;
#pragma unroll
  for (int i = 0; i < 4; ++i) {
    int fl = i * 1024 + t * 4;    // e-major
    int e = fl >> 6, nn = fl & 63;
    float4 a = *reinterpret_cast<const float4*>(wo + ((size_t)(h * 64 + e) * 1024 + nt * 64 + nn));
    tr[nn + 0][e] = (__bf16)a.x; tr[nn + 1][e] = (__bf16)a.y;
    tr[nn + 2][e] = (__bf16)a.z; tr[nn + 3][e] = (__bf16)a.w;
  }
  __syncthreads();
#pragma unroll
  for (int i = 0; i < 2; ++i) {
    int ch = i * 256 + t;
    int nn = ch >> 3, c8 = ch & 7;
    *reinterpret_cast<bf16x8_t*>(out + ((size_t)(nt * 64 + nn) * 1024 + h * 64 + c8 * 8)) =
        *reinterpret_cast<const bf16x8_t*>(&tr[nn][c8 * 8]);
  }
}

__global__ __launch_bounds__(256) void k_bias1(const float* __restrict__ bq,
                                               const float* __restrict__ bk,
                                               const float* __restrict__ bv,
                                               float* __restrict__ b1) {
  int n = blockIdx.x * 256 + threadIdx.x;
  if (n >= 3072) return;
  int p = n >> 10, he = n & 1023;
  const float* s = (p == 0) ? bq : (p == 1) ? bk : bv;
  b1[n] = s[he];
}

// ---------------- GEMM: C[M][N] = A[M][K] * Bt[N][K]^T + bias[N] ----------------
// 128x128 tile, BK=32, 4 waves (2x2 of 64x64), 16x16x32 bf16 MFMA.
template <typename OutT>
__global__ __launch_bounds__(256) void k_gemm(const __bf16* __restrict__ A,
                                              const __bf16* __restrict__ Bt,
                                              const float* __restrict__ bias,
                                              OutT* __restrict__ C, int N, int K) {
  __shared__ __bf16 As[128 * 32];
  __shared__ __bf16 Bs[128 * 32];
  int t = threadIdx.x, l = t & 63;
  int lo = l & 15, hi = l >> 4;
  int w = t >> 6;
  int m0 = blockIdx.y * 128, n0 = blockIdx.x * 128;
  int wm = (w >> 1) * 64, wn = (w & 1) * 64;
  f32x4 acc[4][4] = {};
  for (int k0 = 0; k0 < K; k0 += 32) {
    __syncthreads();
#pragma unroll
    for (int it = 0; it < 2; ++it) {
      int idx = it * 256 + t;
      int row = idx >> 2, c = idx & 3;
      int cs = (c ^ (row & 3)) * 8;
      const __bf16* ga = A + (size_t)(m0 + row) * K + k0 + cs;
      const __bf16* gb = Bt + (size_t)(n0 + row) * K + k0 + cs;
      char* la = (char*)As + (it * 256 + (t & ~63)) * 16;
      char* lb = (char*)Bs + (it * 256 + (t & ~63)) * 16;
      GLOAD16(ga, la);
      GLOAD16(gb, lb);
    }
    __syncthreads();
    bf16x8_t af[4], bfr[4];
#pragma unroll
    for (int mi = 0; mi < 4; ++mi) {
      int row = wm + mi * 16 + lo;
      af[mi] = *reinterpret_cast<const bf16x8_t*>((char*)As + row * 64 + ((hi ^ (row & 3)) << 4));
    }
#pragma unroll
    for (int ni = 0; ni < 4; ++ni) {
      int row = wn + ni * 16 + lo;
      bfr[ni] = *reinterpret_cast<const bf16x8_t*>((char*)Bs + row * 64 + ((hi ^ (row & 3)) << 4));
    }
#pragma unroll
    for (int mi = 0; mi < 4; ++mi)
#pragma unroll
      for (int ni = 0; ni < 4; ++ni)
        acc[mi][ni] = __builtin_amdgcn_mfma_f32_16x16x32_bf16(af[mi], bfr[ni], acc[mi][ni], 0, 0, 0);
  }
#pragma unroll
  for (int ni = 0; ni < 4; ++ni) {
    int n = n0 + wn + ni * 16 + lo;
    float bv = bias[n];
#pragma unroll
    for (int mi = 0; mi < 4; ++mi) {
#pragma unroll
      for (int r = 0; r < 4; ++r) {
        int m = m0 + wm + mi * 16 + hi * 4 + r;
        C[(size_t)m * N + n] = (OutT)(acc[mi][ni][r] + bv);
      }
    }
  }
}

// ---------------- causal flash attention ----------------
// QKV [4096][3072] bf16 (Q at col 0, K at 1024, V at 2048; col = h*64+e within each).
// Z [4096][1024] bf16 (col = h*64+e). 64-row Q tile per block, 64-col KV tiles.
__global__ __launch_bounds__(256) void k_attn(const __bf16* __restrict__ QKV,
                                              __bf16* __restrict__ Z) {
  __shared__ __bf16 Ks[64 * 64];   // swizzled (chunk ^= row&7)
  __shared__ __bf16 Vt[64 * 72];   // [e][kv], padded stride 72
  __shared__ __bf16 Ps[64 * 64];   // swizzled, wave-private rows
  int t = threadIdx.x, l = t & 63, w = t >> 6;
  int lo = l & 15, hi = l >> 4;
  int bh = blockIdx.y;
  int b = bh >> 4, h = bh & 15;
  int q0 = (int)(gridDim.x - 1 - blockIdx.x) * 64;  // long blocks dispatch first

  const __bf16* qptr = QKV + (size_t)(b * 2048 + q0 + w * 16 + lo) * 3072 + h * 64;
  bf16x8_t qf[2];
  qf[0] = *reinterpret_cast<const bf16x8_t*>(qptr + hi * 8);
  qf[1] = *reinterpret_cast<const bf16x8_t*>(qptr + 32 + hi * 8);

  f32x4 zacc[4] = {};
  float mrow[4] = {-1e30f, -1e30f, -1e30f, -1e30f};
  float lrun[4] = {0.f, 0.f, 0.f, 0.f};
  int nt = q0 / 64 + 1;

  for (int tile = 0; tile < nt; ++tile) {
    int kv0 = tile * 64;
    // stage K (global_load_lds, source pre-swizzled)
#pragma unroll
    for (int it = 0; it < 2; ++it) {
      int idx = it * 256 + t;
      int row = idx >> 3, c = idx & 7;
      const __bf16* gk =
          QKV + (size_t)(b * 2048 + kv0 + row) * 3072 + 1024 + h * 64 + ((c ^ (row & 7)) * 8);
      GLOAD16(gk, (char*)Ks + (it * 256 + (t & ~63)) * 16);
    }
    // stage V transposed (reg-staged)
#pragma unroll
    for (int it = 0; it < 2; ++it) {
      int idx = it * 256 + t;
      int kv = idx >> 3, c = idx & 7;
      bf16x8_t v = *reinterpret_cast<const bf16x8_t*>(
          QKV + (size_t)(b * 2048 + kv0 + kv) * 3072 + 2048 + h * 64 + c * 8);
#pragma unroll
      for (int j = 0; j < 8; ++j) Vt[(c * 8 + j) * 72 + kv] = v[j];
    }
    __syncthreads();
    // QK^T
    f32x4 sfr[4];
#pragma unroll
    for (int cb = 0; cb < 4; ++cb) {
      sfr[cb] = f32x4{0.f, 0.f, 0.f, 0.f};
#pragma unroll
      for (int ds = 0; ds < 2; ++ds) {
        int row = cb * 16 + lo;
        int ch = ds * 4 + hi;
        bf16x8_t kf =
            *reinterpret_cast<const bf16x8_t*>((char*)Ks + row * 128 + ((ch ^ (row & 7)) << 4));
        sfr[cb] = __builtin_amdgcn_mfma_f32_16x16x32_bf16(qf[ds], kf, sfr[cb], 0, 0, 0);
      }
    }
    // scale + causal mask + tile row-max
    bool diag = (tile == nt - 1);
    float mt[4] = {-1e30f, -1e30f, -1e30f, -1e30f};
#pragma unroll
    for (int cb = 0; cb < 4; ++cb) {
#pragma unroll
      for (int r = 0; r < 4; ++r) {
        float v = sfr[cb][r] * 0.125f;
        if (diag && (kv0 + cb * 16 + lo > q0 + w * 16 + hi * 4 + r)) v = -1e30f;
        sfr[cb][r] = v;
        mt[r] = fmaxf(mt[r], v);
      }
    }
#pragma unroll
    for (int r = 0; r < 4; ++r) {
      mt[r] = fmaxf(mt[r], __shfl_xor(mt[r], 8));
      mt[r] = fmaxf(mt[r], __shfl_xor(mt[r], 4));
      mt[r] = fmaxf(mt[r], __shfl_xor(mt[r], 2));
      mt[r] = fmaxf(mt[r], __shfl_xor(mt[r], 1));
    }
    float alpha[4], psum[4];
#pragma unroll
    for (int r = 0; r < 4; ++r) {
      float mnew = fmaxf(mrow[r], mt[r]);
      alpha[r] = __expf(mrow[r] - mnew);
      mrow[r] = mnew;
      psum[r] = 0.f;
    }
#pragma unroll
    for (int cb = 0; cb < 4; ++cb)
#pragma unroll
      for (int r = 0; r < 4; ++r) {
        float p = __expf(sfr[cb][r] - mrow[r]);
        sfr[cb][r] = p;
        psum[r] += p;
      }
#pragma unroll
    for (int r = 0; r < 4; ++r) {
      psum[r] += __shfl_xor(psum[r], 8);
      psum[r] += __shfl_xor(psum[r], 4);
      psum[r] += __shfl_xor(psum[r], 2);
      psum[r] += __shfl_xor(psum[r], 1);
      lrun[r] = lrun[r] * alpha[r] + psum[r];
    }
#pragma unroll
    for (int e0 = 0; e0 < 4; ++e0)
#pragma unroll
      for (int r = 0; r < 4; ++r) zacc[e0][r] *= alpha[r];
    // P -> LDS (bf16, swizzled; wave-private rows, no barrier needed)
#pragma unroll
    for (int cb = 0; cb < 4; ++cb) {
      int kvl = cb * 16 + lo;
      int chp = kvl >> 3, wi = kvl & 7;
#pragma unroll
      for (int r = 0; r < 4; ++r) {
        int row = w * 16 + hi * 4 + r;
        *reinterpret_cast<__bf16*>((char*)Ps + row * 128 + ((chp ^ (row & 7)) << 4) + wi * 2) =
            (__bf16)sfr[cb][r];
      }
    }
    // PV
#pragma unroll
    for (int ks = 0; ks < 2; ++ks) {
      int arow = w * 16 + lo;
      bf16x8_t pf = *reinterpret_cast<const bf16x8_t*>(
          (char*)Ps + arow * 128 + (((ks * 4 + hi) ^ (arow & 7)) << 4));
#pragma unroll
      for (int e0 = 0; e0 < 4; ++e0) {
        bf16x8_t vf = *reinterpret_cast<const bf16x8_t*>(&Vt[(e0 * 16 + lo) * 72 + ks * 32 + hi * 8]);
        zacc[e0] = __builtin_amdgcn_mfma_f32_16x16x32_bf16(pf, vf, zacc[e0], 0, 0, 0);
      }
    }
    __syncthreads();
  }
  // epilogue: normalize + store
#pragma unroll
  for (int r = 0; r < 4; ++r) {
    float inv = 1.f / lrun[r];
    size_t row = (size_t)(b * 2048 + q0 + w * 16 + hi * 4 + r);
#pragma unroll
    for (int e0 = 0; e0 < 4; ++e0) {
      Z[row * 1024 + h * 64 + e0 * 16 + lo] = (__bf16)(zacc[e0][r] * inv);
    }
  }
}

// ---------------- launch ----------------

extern "C" void kernel_launch(void* const* d_in, const int* in_sizes, int n_in,
                              void* d_out, int out_size, void* d_ws, size_t ws_size,
                              hipStream_t stream) {
  const float* x  = (const float*)d_in[0];
  const float* wq = (const float*)d_in[1];
  const float* wk = (const float*)d_in[2];
  const float* wv = (const float*)d_in[3];
  const float* wo = (const float*)d_in[4];
  const float* bq = (const float*)d_in[5];
  const float* bk = (const float*)d_in[6];
  const float* bv = (const float*)d_in[7];
  const float* bo = (const float*)d_in[8];
  float* out = (float*)d_out;

  char* ws = (char*)d_ws;
  __bf16* Xb  = (__bf16*)(ws);                 //  8388608 B  [4096][1024]
  __bf16* WB1 = (__bf16*)(ws + 8388608);       //  6291456 B  [3072][1024]
  float*  B1  = (float*)(ws + 14680064);       //    12288 B  [3072]
  __bf16* WB2 = (__bf16*)(ws + 14692352);      //  2097152 B  [1024][1024]
  __bf16* QKV = (__bf16*)(ws + 16789504);      // 25165824 B  [4096][3072]
  __bf16* Zb  = Xb;                            // overlay: X dead after GEMM1

  k_cvt_x<<<4096, 256, 0, stream>>>(x, Xb, 1048576);
  k_packw1<<<dim3(16, 16, 3), 256, 0, stream>>>(wq, wk, wv, WB1);
  k_packw2<<<dim3(16, 16), 256, 0, stream>>>(wo, WB2);
  k_bias1<<<12, 256, 0, stream>>>(bq, bk, bv, B1);

  k_gemm<__bf16><<<dim3(24, 32), 256, 0, stream>>>(Xb, WB1, B1, QKV, 3072, 1024);
  k_attn<<<dim3(32, 32), 256, 0, stream>>>(QKV, Zb);
  k_gemm<float><<<dim3(8, 32), 256, 0, stream>>>(Zb, WB2, bo, out, 1024, 1024);
}